// Round 4
// baseline (1002.231 us; speedup 1.0000x reference)
//
#include <hip/hip_runtime.h>

#define HW 4096

// ---------------- kernel A: per-(q,r,ns,c) instance-norm stats ----------------
__global__ __launch_bounds__(256) void k_stats(const float* __restrict__ corr,
                                               float* __restrict__ scl,
                                               float* __restrict__ shf) {
  int g = blockIdx.x;  // 0..9215  linear over [q][r][ns][c]
  const float4* p = (const float4*)(corr + (size_t)g * HW);
  int t = threadIdx.x;
  float s = 0.f, s2 = 0.f;
#pragma unroll
  for (int i = 0; i < 4; i++) {
    float4 v = p[t + i * 256];
    s += v.x + v.y + v.z + v.w;
    s2 += v.x * v.x + v.y * v.y + v.z * v.z + v.w * v.w;
  }
#pragma unroll
  for (int o = 32; o > 0; o >>= 1) {
    s += __shfl_down(s, o, 64);
    s2 += __shfl_down(s2, o, 64);
  }
  __shared__ float ls[4], ls2[4];
  int wid = t >> 6;
  if ((t & 63) == 0) { ls[wid] = s; ls2[wid] = s2; }
  __syncthreads();
  if (t == 0) {
    float S = ls[0] + ls[1] + ls[2] + ls[3];
    float S2 = ls2[0] + ls2[1] + ls2[2] + ls2[3];
    float m = S * (1.f / HW);
    float var = S2 * (1.f / HW) - m * m;
    float r = rsqrtf(var + 1e-5f);
    scl[g] = r;
    shf[g] = -m * r;
  }
}

// ------- weight transpose for big convs: [oc][ic][9] -> [ic*9+j][oc] -------
__global__ __launch_bounds__(256) void k_wt(const float* __restrict__ p0,
                                            const float* __restrict__ p1,
                                            const float* __restrict__ p2,
                                            const float* __restrict__ p3,
                                            const float* __restrict__ p4,
                                            const float* __restrict__ p5,
                                            float* __restrict__ wT) {
  int b = blockIdx.x;  // 96 = 6 arrays x 16 chunks
  int arr = b >> 4;
  int chunk = b & 15;
  const float* src = (arr == 0) ? p0
                     : (arr == 1) ? p1
                     : (arr == 2) ? p2
                     : (arr == 3) ? p3
                     : (arr == 4) ? p4 : p5;
  float* dst = wT + arr * 36864;
  int t = threadIdx.x;
#pragma unroll
  for (int i = 0; i < 9; i++) {
    int e = chunk * 2304 + i * 256 + t;  // 0..36863
    int oc = e / 576;
    int rem = e - oc * 576;  // ic*9+j
    dst[rem * 64 + oc] = src[e];
  }
}

// ======== k_fused: refscore + top4 + gather + both MLPs + ns-max =========
// grid 256 = q(4) x pxc(64); block 256 = ns-wave(4) x 64 px
__global__ __launch_bounds__(256) void k_fused(
    const float* __restrict__ corr, const float* __restrict__ scl,
    const float* __restrict__ shf,
    const float* __restrict__ w1s, const float* __restrict__ b1s,
    const float* __restrict__ w2s, const float* __restrict__ b2s,
    const float* __restrict__ w1c, const float* __restrict__ b1c,
    const float* __restrict__ w2c, const float* __restrict__ b2c,
    float* __restrict__ xs, float* __restrict__ xc) {
  __shared__ float ls[4 * 576];   // [ns][r*18+c] scl
  __shared__ float lsh[4 * 576];  // shift
  __shared__ float lshT[4 * 32];  // sum_c shf per (ns,r)
  __shared__ float red8[8 * 256];
  int blk = blockIdx.x;
  int q = blk >> 6;
  int pxc = blk & 63;
  int t = threadIdx.x;
  int ns = t >> 6;       // wave-uniform
  int lane = t & 63;
  int px = pxc * 64 + lane;

  // stage scl/shf for this q: global j = r*72 + ns*18 + c
  for (int j = t; j < 2304; j += 256) {
    int r = j / 72;
    int rem = j - r * 72;
    int nsj = rem / 18;
    int c = rem - nsj * 18;
    ls[nsj * 576 + r * 18 + c] = scl[q * 2304 + j];
    lsh[nsj * 576 + r * 18 + c] = shf[q * 2304 + j];
  }
  __syncthreads();
  if (t < 128) {
    int nsj = t >> 5, r = t & 31;
    float s = 0.f;
#pragma unroll
    for (int c = 0; c < 18; c++) s += lsh[nsj * 576 + r * 18 + c];
    lshT[nsj * 32 + r] = s;
  }
  __syncthreads();

  // pass 1: rs (un-divided; ordering identical) — coalesced full stream
  const float* bp = corr + ((size_t)(q * 2304) + ns * 18) * HW + px;
  float rsv[32];
#pragma unroll
  for (int r = 0; r < 32; r++) {
    float a = 0.f;
#pragma unroll
    for (int c = 0; c < 18; c++)
      a += bp[(size_t)(r * 72 + c) * HW] * ls[ns * 576 + r * 18 + c];
    rsv[r] = a + lshT[ns * 32 + r];
  }
  // top-4 (jax tie semantics: strict >, ascending index)
  unsigned mask = 0;
  int sel[4];
#pragma unroll
  for (int k = 0; k < 4; k++) {
    float best = -3.4e38f;
    int bi = 0;
#pragma unroll
    for (int r = 0; r < 32; r++) {
      bool take = (!(mask & (1u << r))) && (rsv[r] > best);
      best = take ? rsv[r] : best;
      bi = take ? r : bi;
    }
    sel[k] = bi;
    mask |= (1u << bi);
  }
  // pass 2: gather 4 selected rows (L2-hot) + normalize
  float v[72];
#pragma unroll
  for (int k = 0; k < 4; k++) {
    int rk = sel[k];
    const float* cp = corr + ((size_t)(q * 2304) + rk * 72 + ns * 18) * HW + px;
#pragma unroll
    for (int c = 0; c < 18; c++)
      v[k * 18 + c] =
          cp[(size_t)c * HW] * ls[ns * 576 + rk * 18 + c] + lsh[ns * 576 + rk * 18 + c];
  }
  float xsc[12];
#pragma unroll
  for (int k = 0; k < 4; k++)
#pragma unroll
    for (int l = 0; l < 3; l++) {
      float s = 0.f;
#pragma unroll
      for (int j = 0; j < 6; j++) s += v[k * 18 + l * 6 + j];
      xsc[k * 3 + l] = s * (1.f / 6.f);
    }

  // ---- scale path: L1 (72->64) all-register, 8 independent acc ----
  float h[64];
#pragma unroll
  for (int og = 0; og < 8; og++) {
    float a[8];
#pragma unroll
    for (int j = 0; j < 8; j++) a[j] = b1s[og * 8 + j];
#pragma unroll
    for (int c = 0; c < 72; c++) {
      float x = v[c];
#pragma unroll
      for (int j = 0; j < 8; j++) a[j] += w1s[(og * 8 + j) * 72 + c] * x;
    }
#pragma unroll
    for (int j = 0; j < 8; j++) h[og * 8 + j] = fmaxf(a[j], 0.f);
  }
  // ---- scale path: L2 (64->64) + ns-max ----
#pragma unroll
  for (int og = 0; og < 8; og++) {
    float a[8];
#pragma unroll
    for (int j = 0; j < 8; j++) a[j] = b2s[og * 8 + j];
#pragma unroll
    for (int c = 0; c < 64; c++) {
      float x = h[c];
#pragma unroll
      for (int j = 0; j < 8; j++) a[j] += w2s[(og * 8 + j) * 64 + c] * x;
    }
#pragma unroll
    for (int j = 0; j < 8; j++) red8[j * 256 + t] = a[j];
    __syncthreads();
#pragma unroll
    for (int jj = 0; jj < 2; jj++) {
      int j2 = (t >> 6) * 2 + jj;
      float m = red8[j2 * 256 + lane];
#pragma unroll
      for (int n2 = 1; n2 < 4; n2++)
        m = fmaxf(m, red8[j2 * 256 + n2 * 64 + lane]);
      xs[(size_t)(q * 64 + og * 8 + j2) * HW + px] = m;
    }
    __syncthreads();
  }
  // ---- score path: L1 (12->64) ----
#pragma unroll
  for (int og = 0; og < 8; og++) {
    float a[8];
#pragma unroll
    for (int j = 0; j < 8; j++) a[j] = b1c[og * 8 + j];
#pragma unroll
    for (int c = 0; c < 12; c++) {
      float x = xsc[c];
#pragma unroll
      for (int j = 0; j < 8; j++) a[j] += w1c[(og * 8 + j) * 12 + c] * x;
    }
#pragma unroll
    for (int j = 0; j < 8; j++) h[og * 8 + j] = fmaxf(a[j], 0.f);
  }
  // ---- score path: L2 (64->64) + ns-max ----
#pragma unroll
  for (int og = 0; og < 8; og++) {
    float a[8];
#pragma unroll
    for (int j = 0; j < 8; j++) a[j] = b2c[og * 8 + j];
#pragma unroll
    for (int c = 0; c < 64; c++) {
      float x = h[c];
#pragma unroll
      for (int j = 0; j < 8; j++) a[j] += w2c[(og * 8 + j) * 64 + c] * x;
    }
#pragma unroll
    for (int j = 0; j < 8; j++) red8[j * 256 + t] = a[j];
    __syncthreads();
#pragma unroll
    for (int jj = 0; jj < 2; jj++) {
      int j2 = (t >> 6) * 2 + jj;
      float m = red8[j2 * 256 + lane];
#pragma unroll
      for (int n2 = 1; n2 < 4; n2++)
        m = fmaxf(m, red8[j2 * 256 + n2 * 64 + lane]);
      xc[(size_t)(q * 64 + og * 8 + j2) * HW + px] = m;
    }
    __syncthreads();
  }
}

// ---- big 3x3 conv, 64ic->64oc, transposed weights -> s_load_dwordx8 ----
template <bool RELU>
__global__ __launch_bounds__(256) void k_conv64T(const float* __restrict__ in,
                                                 const float* __restrict__ wT,
                                                 const float* __restrict__ bias,
                                                 float* __restrict__ out) {
  __shared__ float tile[16 * 6 * 66];  // 25.3 KB
  int b = blockIdx.x;                  // 512 = q(4) x rt(16) x og(8)
  int og = b & 7;
  int rt = (b >> 3) & 15;
  int q = b >> 7;
  int t = threadIdx.x;
  int w = t & 63;
  int wr = t >> 6;  // wave-uniform
  float acc[8] = {0.f, 0.f, 0.f, 0.f, 0.f, 0.f, 0.f, 0.f};
  if (t < 96) { tile[t * 66] = 0.f; tile[t * 66 + 65] = 0.f; }
  const float* inq = in + (size_t)q * 64 * HW;
  for (int icc = 0; icc < 4; icc++) {
    __syncthreads();
#pragma unroll
    for (int p = 0; p < 24; p++) {
      int idx = p * 4 + wr;  // ch*6 + r, 0..95 (uniform)
      int r = idx % 6;
      int ch = idx / 6;
      int grow = rt * 4 + r - 1;
      float val = 0.f;
      if (grow >= 0 && grow < 64)
        val = inq[(size_t)(icc * 16 + ch) * HW + grow * 64 + w];
      tile[idx * 66 + 1 + w] = val;
    }
    __syncthreads();
#pragma unroll 2
    for (int ic = 0; ic < 16; ic++) {
      float x[9];
#pragma unroll
      for (int dr = 0; dr < 3; dr++)
#pragma unroll
        for (int dc = 0; dc < 3; dc++)
          x[dr * 3 + dc] = tile[(ic * 6 + wr + dr) * 66 + w + dc];
      // 8 contiguous oc-weights per tap: one s_load_dwordx8 each
      const float* wb = wT + (size_t)(icc * 16 + ic) * 9 * 64 + og * 8;
#pragma unroll
      for (int j = 0; j < 9; j++) {
        const float* wv = wb + j * 64;
#pragma unroll
        for (int o = 0; o < 8; o++) acc[o] += wv[o] * x[j];
      }
    }
  }
  int orow = rt * 4 + wr;
#pragma unroll
  for (int o = 0; o < 8; o++) {
    float rz = acc[o] + bias[og * 8 + o];
    if (RELU) rz = fmaxf(rz, 0.f);
    out[((size_t)q * 64 + og * 8 + o) * HW + orow * 64 + w] = rz;
  }
}

// ---- small 3x3 conv (OC=1,2): 1-row blocks, all 64 ic staged once ----
template <int OC>
__global__ __launch_bounds__(256) void k_convS(const float* __restrict__ in,
                                               const float* __restrict__ wt,
                                               const float* __restrict__ bias,
                                               float* __restrict__ out) {
  __shared__ float tile[64 * 3 * 66];  // 50.7 KB
  __shared__ float red[4 * OC * 64];
  int b = blockIdx.x;  // 256 = q(4) x row(64)
  int row = b & 63;
  int q = b >> 6;
  int t = threadIdx.x;
  int w = t & 63;
  int sub = t >> 6;  // ic quarter (wave-uniform)
  if (t < 192) { tile[t * 66] = 0.f; tile[t * 66 + 65] = 0.f; }
  __syncthreads();
  const float* inq = in + (size_t)q * 64 * HW;
#pragma unroll
  for (int i = 0; i < 48; i++) {
    int idx = i * 4 + sub;  // ic*3 + r (uniform)
    int ic = idx / 3;
    int r = idx - ic * 3;
    int grow = row + r - 1;
    float val = 0.f;
    if (grow >= 0 && grow < 64) val = inq[(size_t)ic * HW + grow * 64 + w];
    tile[idx * 66 + 1 + w] = val;
  }
  __syncthreads();
  float acc[OC];
#pragma unroll
  for (int o = 0; o < OC; o++) acc[o] = 0.f;
#pragma unroll 4
  for (int i = 0; i < 16; i++) {
    int ic = sub * 16 + i;
    float x[9];
#pragma unroll
    for (int dr = 0; dr < 3; dr++)
#pragma unroll
      for (int dc = 0; dc < 3; dc++)
        x[dr * 3 + dc] = tile[(ic * 3 + dr) * 66 + w + dc];
    const float* wb = wt + (size_t)ic * 9;
#pragma unroll
    for (int o = 0; o < OC; o++) {
      const float* wp = wb + o * 576;
#pragma unroll
      for (int j = 0; j < 9; j++) acc[o] += wp[j] * x[j];
    }
  }
#pragma unroll
  for (int o = 0; o < OC; o++) red[(sub * OC + o) * 64 + w] = acc[o];
  __syncthreads();
  if (t < 64 * OC) {
    int o = t >> 6;
    float s = red[(0 * OC + o) * 64 + w] + red[(1 * OC + o) * 64 + w] +
              red[(2 * OC + o) * 64 + w] + red[(3 * OC + o) * 64 + w] + bias[o];
    out[((size_t)q * OC + o) * HW + row * 64 + w] = s;
  }
}

// ---------------- final: argmax + pos/scl ----------------
__global__ __launch_bounds__(256) void k_final(const float* __restrict__ scores,
                                               const float* __restrict__ scales,
                                               const float* __restrict__ offsets,
                                               float* __restrict__ pos,
                                               float* __restrict__ sclo) {
  int q = blockIdx.x, t = threadIdx.x;
  float best = -3.4e38f;
  int bi = 1 << 30;
  for (int i = t; i < HW; i += 256) {
    float v = scores[q * HW + i];
    if (v > best) { best = v; bi = i; }
  }
  __shared__ float bv[256];
  __shared__ int bix[256];
  bv[t] = best;
  bix[t] = bi;
  __syncthreads();
  for (int s = 128; s > 0; s >>= 1) {
    if (t < s) {
      if (bv[t + s] > bv[t] || (bv[t + s] == bv[t] && bix[t + s] < bix[t])) {
        bv[t] = bv[t + s];
        bix[t] = bix[t + s];
      }
    }
    __syncthreads();
  }
  if (t == 0) {
    int sid = bix[0];
    int sy = sid >> 6, sx = sid & 63;
    float o0 = offsets[(q * 2 + 0) * HW + sid];
    float o1 = offsets[(q * 2 + 1) * HW + sid];
    pos[q * 2 + 0] = ((float)sx + o0 + 0.5f) * 8.f - 0.5f;
    pos[q * 2 + 1] = ((float)sy + o1 + 0.5f) * 8.f - 0.5f;
    sclo[q] = exp2f(scales[q * HW + sid]);
  }
}

extern "C" void kernel_launch(void* const* d_in, const int* in_sizes, int n_in,
                              void* d_out, int out_size, void* d_ws, size_t ws_size,
                              hipStream_t stream) {
  const float* corr = (const float*)d_in[0];
  const float* w1s = (const float*)d_in[1];
  const float* b1s = (const float*)d_in[2];
  const float* w2s = (const float*)d_in[3];
  const float* b2s = (const float*)d_in[4];
  const float* w1c = (const float*)d_in[5];
  const float* b1c = (const float*)d_in[6];
  const float* w2c = (const float*)d_in[7];
  const float* b2c = (const float*)d_in[8];

  float* out = (float*)d_out;
  float* pos = out;                   // (4,2)
  float* sclo = out + 8;              // (4,)
  float* scores = out + 12;           // (4,1,64,64)
  float* scales = out + 12 + 16384;   // (4,1,64,64)
  float* offsets = out + 12 + 32768;  // (4,2,64,64)

  char* ws = (char*)d_ws;
  float* st_scl = (float*)(ws + 0);        // 36 KB
  float* st_shf = (float*)(ws + 36864);    // 36 KB
  float* wT = (float*)(ws + 73728);        // 6 x 147456 B = 884736 B
  float* xs = (float*)(ws + 958464);       // 4.19 MB
  float* xc = (float*)(ws + 5152768);      // 4.19 MB
  float* t1 = (float*)(ws + 9347072);      // 4.19 MB
  float* t2 = (float*)(ws + 13541376);     // 4.19 MB  (total 17.7 MB)

  k_wt<<<96, 256, 0, stream>>>((const float*)d_in[9], (const float*)d_in[11],
                               (const float*)d_in[15], (const float*)d_in[17],
                               (const float*)d_in[21], (const float*)d_in[23], wT);
  k_stats<<<9216, 256, 0, stream>>>(corr, st_scl, st_shf);
  k_fused<<<256, 256, 0, stream>>>(corr, st_scl, st_shf, w1s, b1s, w2s, b2s,
                                   w1c, b1c, w2c, b2c, xs, xc);
  // scale head -> scales
  k_conv64T<true><<<512, 256, 0, stream>>>(xs, wT + 0 * 36864, (const float*)d_in[10], t1);
  k_conv64T<true><<<512, 256, 0, stream>>>(t1, wT + 1 * 36864, (const float*)d_in[12], t2);
  k_convS<1><<<256, 256, 0, stream>>>(t2, (const float*)d_in[13], (const float*)d_in[14], scales);
  // offset head -> offsets
  k_conv64T<true><<<512, 256, 0, stream>>>(xc, wT + 2 * 36864, (const float*)d_in[16], t1);
  k_conv64T<true><<<512, 256, 0, stream>>>(t1, wT + 3 * 36864, (const float*)d_in[18], t2);
  k_convS<2><<<256, 256, 0, stream>>>(t2, (const float*)d_in[19], (const float*)d_in[20], offsets);
  // score head -> scores
  k_conv64T<true><<<512, 256, 0, stream>>>(xc, wT + 4 * 36864, (const float*)d_in[22], t1);
  k_conv64T<true><<<512, 256, 0, stream>>>(t1, wT + 5 * 36864, (const float*)d_in[24], t2);
  k_convS<1><<<256, 256, 0, stream>>>(t2, (const float*)d_in[25], (const float*)d_in[26], scores);

  k_final<<<4, 256, 0, stream>>>(scores, scales, offsets, pos, sclo);
}

// Round 5
// 844.193 us; speedup vs baseline: 1.1872x; 1.1872x over previous
//
#include <hip/hip_runtime.h>

#define HW 4096

// ---------------- kernel A: per-(q,r,ns,c) instance-norm stats ----------------
__global__ __launch_bounds__(256) void k_stats(const float* __restrict__ corr,
                                               float* __restrict__ scl,
                                               float* __restrict__ shf) {
  int g = blockIdx.x;  // 0..9215  linear over [q][r][ns][c]
  const float4* p = (const float4*)(corr + (size_t)g * HW);
  int t = threadIdx.x;
  float s = 0.f, s2 = 0.f;
#pragma unroll
  for (int i = 0; i < 4; i++) {
    float4 v = p[t + i * 256];
    s += v.x + v.y + v.z + v.w;
    s2 += v.x * v.x + v.y * v.y + v.z * v.z + v.w * v.w;
  }
#pragma unroll
  for (int o = 32; o > 0; o >>= 1) {
    s += __shfl_down(s, o, 64);
    s2 += __shfl_down(s2, o, 64);
  }
  __shared__ float ls[4], ls2[4];
  int wid = t >> 6;
  if ((t & 63) == 0) { ls[wid] = s; ls2[wid] = s2; }
  __syncthreads();
  if (t == 0) {
    float S = ls[0] + ls[1] + ls[2] + ls[3];
    float S2 = ls2[0] + ls2[1] + ls2[2] + ls2[3];
    float m = S * (1.f / HW);
    float var = S2 * (1.f / HW) - m * m;
    float r = rsqrtf(var + 1e-5f);
    scl[g] = r;
    shf[g] = -m * r;
  }
}

// ------- weight transpose for big convs: [oc][ic][9] -> [ic*9+j][oc] -------
__global__ __launch_bounds__(256) void k_wt(const float* __restrict__ p0,
                                            const float* __restrict__ p1,
                                            const float* __restrict__ p2,
                                            const float* __restrict__ p3,
                                            const float* __restrict__ p4,
                                            const float* __restrict__ p5,
                                            float* __restrict__ wT) {
  int b = blockIdx.x;  // 96 = 6 arrays x 16 chunks
  int arr = b >> 4;
  int chunk = b & 15;
  const float* src = (arr == 0) ? p0
                     : (arr == 1) ? p1
                     : (arr == 2) ? p2
                     : (arr == 3) ? p3
                     : (arr == 4) ? p4 : p5;
  float* dst = wT + arr * 36864;
  int t = threadIdx.x;
#pragma unroll
  for (int i = 0; i < 9; i++) {
    int e = chunk * 2304 + i * 256 + t;  // 0..36863
    int oc = e / 576;
    int rem = e - oc * 576;  // ic*9+j
    dst[rem * 64 + oc] = src[e];
  }
}

// ---------------- kernel B: ref_score -> rs[(q*32+r)*4+ns][px] ----------------
__global__ __launch_bounds__(256) void k_refscore(const float* __restrict__ corr,
                                                  const float* __restrict__ scl,
                                                  const float* __restrict__ shf,
                                                  float* __restrict__ rs) {
  int b = blockIdx.x;     // 2048
  int grp = b >> 2;       // 0..511
  int i4 = (b & 3) * 256 + threadIdx.x;  // float4 index 0..1023
  const float* base = corr + (size_t)grp * 18 * HW;
  float4 acc = make_float4(0.f, 0.f, 0.f, 0.f);
  float sh = 0.f;
#pragma unroll
  for (int c = 0; c < 18; c++) {
    float s = scl[grp * 18 + c];
    sh += shf[grp * 18 + c];
    float4 v = ((const float4*)(base + c * HW))[i4];
    acc.x += v.x * s; acc.y += v.y * s; acc.z += v.z * s; acc.w += v.w * s;
  }
  const float inv = 1.f / 18.f;
  float4 o;
  o.x = (acc.x + sh) * inv; o.y = (acc.y + sh) * inv;
  o.z = (acc.z + sh) * inv; o.w = (acc.w + sh) * inv;
  ((float4*)(rs + (size_t)grp * HW))[i4] = o;
}

// ---------------- kernel C: top-4 of 32, LDS-staged ----------------
__global__ __launch_bounds__(256) void k_topk(const float* __restrict__ rs,
                                              int* __restrict__ topidx) {
  __shared__ float st[32 * 256];  // 32 KB
  int b = blockIdx.x;             // 256 = q*4ns*16pxc
  int pxc = b & 15;
  int ns = (b >> 4) & 3;
  int q = b >> 6;
  int t = threadIdx.x;
  int pxb = pxc * 256;
#pragma unroll 8
  for (int r = 0; r < 32; r++)
    st[r * 256 + t] = rs[((q * 32 + r) * 4 + ns) * HW + pxb + t];
  __syncthreads();
  float v[32];
#pragma unroll
  for (int r = 0; r < 32; r++) v[r] = st[r * 256 + t];
  unsigned mask = 0;
  int sel[4];
#pragma unroll
  for (int k = 0; k < 4; k++) {
    float best = -3.4e38f;
    int bi = 0;
#pragma unroll
    for (int r = 0; r < 32; r++) {
      bool take = (!(mask & (1u << r))) && (v[r] > best);
      best = take ? v[r] : best;
      bi = take ? r : bi;
    }
    sel[k] = bi;
    mask |= (1u << bi);
  }
  ((int4*)topidx)[(q * 4 + ns) * HW + pxb + t] =
      make_int4(sel[0], sel[1], sel[2], sel[3]);
}

// -------- kernel D1: high-occupancy streaming gather+norm -> vbuf ----------
__global__ __launch_bounds__(256) void k_gather(const float* __restrict__ corr,
                                                const float* __restrict__ scl,
                                                const float* __restrict__ shf,
                                                const int* __restrict__ topidx,
                                                float* __restrict__ vbuf) {
  __shared__ float ls[32], lsh[32];
  int b = blockIdx.x;  // 4608 = q x pxc x ns x c
  int c = b % 18;
  int rest = b / 18;
  int ns = rest & 3;
  int pxc = (rest >> 2) & 15;
  int q = rest >> 6;
  int t = threadIdx.x;
  int px = pxc * 256 + t;

  if (t < 32) {
    int g = q * 2304 + t * 72 + ns * 18 + c;
    ls[t] = scl[g];
    lsh[t] = shf[g];
  }
  int4 ti = ((const int4*)topidx)[(q * 4 + ns) * HW + px];
  int rk0 = ti.x, rk1 = ti.y, rk2 = ti.z, rk3 = ti.w;
  __syncthreads();

  const float* base = corr + (size_t)(((q * 32) * 4 + ns) * 18 + c) * HW + px;
  float v0 = 0.f, v1 = 0.f, v2 = 0.f, v3 = 0.f;
#pragma unroll
  for (int r = 0; r < 32; r++) {
    float x = base[(size_t)r * 72 * HW];
    v0 = (rk0 == r) ? x : v0;
    v1 = (rk1 == r) ? x : v1;
    v2 = (rk2 == r) ? x : v2;
    v3 = (rk3 == r) ? x : v3;
  }
  v0 = v0 * ls[rk0] + lsh[rk0];
  v1 = v1 * ls[rk1] + lsh[rk1];
  v2 = v2 * ls[rk2] + lsh[rk2];
  v3 = v3 * ls[rk3] + lsh[rk3];
  size_t ob = (size_t)((q * 4 + ns) * 72 + c) * HW + px;
  vbuf[ob] = v0;
  vbuf[ob + 18 * HW] = v1;
  vbuf[ob + 36 * HW] = v2;
  vbuf[ob + 54 * HW] = v3;
}

// ---- kernel D2 v3: all-register MLPs (8 indep acc) + ns-max, from vbuf ----
// grid 256 = q(4) x pxc(64); block 256 = ns-wave(4) x 64 px
__global__ __launch_bounds__(256) void k_mlp3(
    const float* __restrict__ vbuf,
    const float* __restrict__ w1s, const float* __restrict__ b1s,
    const float* __restrict__ w2s, const float* __restrict__ b2s,
    const float* __restrict__ w1c, const float* __restrict__ b1c,
    const float* __restrict__ w2c, const float* __restrict__ b2c,
    float* __restrict__ xs, float* __restrict__ xc) {
  __shared__ float red8[8 * 256];
  int blk = blockIdx.x;
  int q = blk >> 6;
  int pxc = blk & 63;
  int t = threadIdx.x;
  int ns = t >> 6;  // wave-uniform
  int lane = t & 63;
  int px = pxc * 64 + lane;

  float v[72];
  const float* vb = vbuf + (size_t)((q * 4 + ns) * 72) * HW + px;
#pragma unroll
  for (int j = 0; j < 72; j++) v[j] = vb[(size_t)j * HW];

  float xsc[12];
#pragma unroll
  for (int k = 0; k < 4; k++)
#pragma unroll
    for (int l = 0; l < 3; l++) {
      float s = 0.f;
#pragma unroll
      for (int j = 0; j < 6; j++) s += v[k * 18 + l * 6 + j];
      xsc[k * 3 + l] = s * (1.f / 6.f);
    }

  // ---- scale path: L1 (72->64), 8 independent acc per group ----
  float h[64];
#pragma unroll
  for (int og = 0; og < 8; og++) {
    float a[8];
#pragma unroll
    for (int j = 0; j < 8; j++) a[j] = b1s[og * 8 + j];
#pragma unroll
    for (int c = 0; c < 72; c++) {
      float x = v[c];
#pragma unroll
      for (int j = 0; j < 8; j++) a[j] += w1s[(og * 8 + j) * 72 + c] * x;
    }
#pragma unroll
    for (int j = 0; j < 8; j++) h[og * 8 + j] = fmaxf(a[j], 0.f);
  }
  // ---- scale path: L2 (64->64) + ns-max ----
#pragma unroll
  for (int og = 0; og < 8; og++) {
    float a[8];
#pragma unroll
    for (int j = 0; j < 8; j++) a[j] = b2s[og * 8 + j];
#pragma unroll
    for (int c = 0; c < 64; c++) {
      float x = h[c];
#pragma unroll
      for (int j = 0; j < 8; j++) a[j] += w2s[(og * 8 + j) * 64 + c] * x;
    }
#pragma unroll
    for (int j = 0; j < 8; j++) red8[j * 256 + t] = a[j];
    __syncthreads();
#pragma unroll
    for (int jj = 0; jj < 2; jj++) {
      int j2 = (t >> 6) * 2 + jj;
      float m = red8[j2 * 256 + lane];
#pragma unroll
      for (int n2 = 1; n2 < 4; n2++)
        m = fmaxf(m, red8[j2 * 256 + n2 * 64 + lane]);
      xs[(size_t)(q * 64 + og * 8 + j2) * HW + px] = m;
    }
    __syncthreads();
  }
  // ---- score path: L1 (12->64) ----
#pragma unroll
  for (int og = 0; og < 8; og++) {
    float a[8];
#pragma unroll
    for (int j = 0; j < 8; j++) a[j] = b1c[og * 8 + j];
#pragma unroll
    for (int c = 0; c < 12; c++) {
      float x = xsc[c];
#pragma unroll
      for (int j = 0; j < 8; j++) a[j] += w1c[(og * 8 + j) * 12 + c] * x;
    }
#pragma unroll
    for (int j = 0; j < 8; j++) h[og * 8 + j] = fmaxf(a[j], 0.f);
  }
  // ---- score path: L2 (64->64) + ns-max ----
#pragma unroll
  for (int og = 0; og < 8; og++) {
    float a[8];
#pragma unroll
    for (int j = 0; j < 8; j++) a[j] = b2c[og * 8 + j];
#pragma unroll
    for (int c = 0; c < 64; c++) {
      float x = h[c];
#pragma unroll
      for (int j = 0; j < 8; j++) a[j] += w2c[(og * 8 + j) * 64 + c] * x;
    }
#pragma unroll
    for (int j = 0; j < 8; j++) red8[j * 256 + t] = a[j];
    __syncthreads();
#pragma unroll
    for (int jj = 0; jj < 2; jj++) {
      int j2 = (t >> 6) * 2 + jj;
      float m = red8[j2 * 256 + lane];
#pragma unroll
      for (int n2 = 1; n2 < 4; n2++)
        m = fmaxf(m, red8[j2 * 256 + n2 * 64 + lane]);
      xc[(size_t)(q * 64 + og * 8 + j2) * HW + px] = m;
    }
    __syncthreads();
  }
}

// ---- big 3x3 conv, 64ic->64oc, transposed weights + XCD-swizzled blocks ----
// og in HIGH bits of blockIdx: all 8 og-siblings of a tile share blockIdx%8
// -> same XCD -> tile stage hits that XCD's L2 for 7 of 8 og groups.
template <bool RELU>
__global__ __launch_bounds__(256) void k_conv64T(const float* __restrict__ in,
                                                 const float* __restrict__ wT,
                                                 const float* __restrict__ bias,
                                                 float* __restrict__ out) {
  __shared__ float tile[16 * 6 * 66];  // 25.3 KB
  int b = blockIdx.x;                  // 512 = og(8) x q(4) x rt(16)
  int og = b >> 6;
  int tl = b & 63;
  int q = tl >> 4;
  int rt = tl & 15;
  int t = threadIdx.x;
  int w = t & 63;
  int wr = t >> 6;  // wave-uniform
  float acc[8] = {0.f, 0.f, 0.f, 0.f, 0.f, 0.f, 0.f, 0.f};
  if (t < 96) { tile[t * 66] = 0.f; tile[t * 66 + 65] = 0.f; }
  const float* inq = in + (size_t)q * 64 * HW;
  for (int icc = 0; icc < 4; icc++) {
    __syncthreads();
#pragma unroll
    for (int p = 0; p < 24; p++) {
      int idx = p * 4 + wr;  // ch*6 + r, 0..95 (uniform)
      int r = idx % 6;
      int ch = idx / 6;
      int grow = rt * 4 + r - 1;
      float val = 0.f;
      if (grow >= 0 && grow < 64)
        val = inq[(size_t)(icc * 16 + ch) * HW + grow * 64 + w];
      tile[idx * 66 + 1 + w] = val;
    }
    __syncthreads();
#pragma unroll 2
    for (int ic = 0; ic < 16; ic++) {
      float x[9];
#pragma unroll
      for (int dr = 0; dr < 3; dr++)
#pragma unroll
        for (int dc = 0; dc < 3; dc++)
          x[dr * 3 + dc] = tile[(ic * 6 + wr + dr) * 66 + w + dc];
      const float* wb = wT + (size_t)(icc * 16 + ic) * 9 * 64 + og * 8;
#pragma unroll
      for (int j = 0; j < 9; j++) {
        const float* wv = wb + j * 64;
#pragma unroll
        for (int o = 0; o < 8; o++) acc[o] += wv[o] * x[j];
      }
    }
  }
  int orow = rt * 4 + wr;
#pragma unroll
  for (int o = 0; o < 8; o++) {
    float rz = acc[o] + bias[og * 8 + o];
    if (RELU) rz = fmaxf(rz, 0.f);
    out[((size_t)q * 64 + og * 8 + o) * HW + orow * 64 + w] = rz;
  }
}

// ---- small 3x3 conv (OC=1,2): 1-row blocks, all 64 ic staged once ----
template <int OC>
__global__ __launch_bounds__(256) void k_convS(const float* __restrict__ in,
                                               const float* __restrict__ wt,
                                               const float* __restrict__ bias,
                                               float* __restrict__ out) {
  __shared__ float tile[64 * 3 * 66];  // 50.7 KB
  __shared__ float red[4 * OC * 64];
  int b = blockIdx.x;  // 256 = q(4) x row(64)
  int row = b & 63;
  int q = b >> 6;
  int t = threadIdx.x;
  int w = t & 63;
  int sub = t >> 6;  // ic quarter (wave-uniform)
  if (t < 192) { tile[t * 66] = 0.f; tile[t * 66 + 65] = 0.f; }
  __syncthreads();
  const float* inq = in + (size_t)q * 64 * HW;
#pragma unroll
  for (int i = 0; i < 48; i++) {
    int idx = i * 4 + sub;  // ic*3 + r (uniform)
    int ic = idx / 3;
    int r = idx - ic * 3;
    int grow = row + r - 1;
    float val = 0.f;
    if (grow >= 0 && grow < 64) val = inq[(size_t)ic * HW + grow * 64 + w];
    tile[idx * 66 + 1 + w] = val;
  }
  __syncthreads();
  float acc[OC];
#pragma unroll
  for (int o = 0; o < OC; o++) acc[o] = 0.f;
#pragma unroll 4
  for (int i = 0; i < 16; i++) {
    int ic = sub * 16 + i;
    float x[9];
#pragma unroll
    for (int dr = 0; dr < 3; dr++)
#pragma unroll
      for (int dc = 0; dc < 3; dc++)
        x[dr * 3 + dc] = tile[(ic * 3 + dr) * 66 + w + dc];
    const float* wb = wt + (size_t)ic * 9;
#pragma unroll
    for (int o = 0; o < OC; o++) {
      const float* wp = wb + o * 576;
#pragma unroll
      for (int j = 0; j < 9; j++) acc[o] += wp[j] * x[j];
    }
  }
#pragma unroll
  for (int o = 0; o < OC; o++) red[(sub * OC + o) * 64 + w] = acc[o];
  __syncthreads();
  if (t < 64 * OC) {
    int o = t >> 6;
    float s = red[(0 * OC + o) * 64 + w] + red[(1 * OC + o) * 64 + w] +
              red[(2 * OC + o) * 64 + w] + red[(3 * OC + o) * 64 + w] + bias[o];
    out[((size_t)q * OC + o) * HW + row * 64 + w] = s;
  }
}

// ---------------- final: argmax + pos/scl ----------------
__global__ __launch_bounds__(256) void k_final(const float* __restrict__ scores,
                                               const float* __restrict__ scales,
                                               const float* __restrict__ offsets,
                                               float* __restrict__ pos,
                                               float* __restrict__ sclo) {
  int q = blockIdx.x, t = threadIdx.x;
  float best = -3.4e38f;
  int bi = 1 << 30;
  for (int i = t; i < HW; i += 256) {
    float v = scores[q * HW + i];
    if (v > best) { best = v; bi = i; }
  }
  __shared__ float bv[256];
  __shared__ int bix[256];
  bv[t] = best;
  bix[t] = bi;
  __syncthreads();
  for (int s = 128; s > 0; s >>= 1) {
    if (t < s) {
      if (bv[t + s] > bv[t] || (bv[t + s] == bv[t] && bix[t + s] < bix[t])) {
        bv[t] = bv[t + s];
        bix[t] = bix[t + s];
      }
    }
    __syncthreads();
  }
  if (t == 0) {
    int sid = bix[0];
    int sy = sid >> 6, sx = sid & 63;
    float o0 = offsets[(q * 2 + 0) * HW + sid];
    float o1 = offsets[(q * 2 + 1) * HW + sid];
    pos[q * 2 + 0] = ((float)sx + o0 + 0.5f) * 8.f - 0.5f;
    pos[q * 2 + 1] = ((float)sy + o1 + 0.5f) * 8.f - 0.5f;
    sclo[q] = exp2f(scales[q * HW + sid]);
  }
}

extern "C" void kernel_launch(void* const* d_in, const int* in_sizes, int n_in,
                              void* d_out, int out_size, void* d_ws, size_t ws_size,
                              hipStream_t stream) {
  const float* corr = (const float*)d_in[0];
  const float* w1s = (const float*)d_in[1];
  const float* b1s = (const float*)d_in[2];
  const float* w2s = (const float*)d_in[3];
  const float* b2s = (const float*)d_in[4];
  const float* w1c = (const float*)d_in[5];
  const float* b1c = (const float*)d_in[6];
  const float* w2c = (const float*)d_in[7];
  const float* b2c = (const float*)d_in[8];

  float* out = (float*)d_out;
  float* pos = out;                   // (4,2)
  float* sclo = out + 8;              // (4,)
  float* scores = out + 12;           // (4,1,64,64)
  float* scales = out + 12 + 16384;   // (4,1,64,64)
  float* offsets = out + 12 + 32768;  // (4,2,64,64)

  char* ws = (char*)d_ws;
  float* st_scl = (float*)(ws + 0);       // 36 KB
  float* st_shf = (float*)(ws + 36864);   // 36 KB
  int* topidx = (int*)(ws + 73728);       // 1 MB
  float* rs = (float*)(ws + 1122304);     // 8.39 MB (dead after k_topk)
  float* vbuf = rs;                       // 18.87 MB, overlaps rs (ok)
  float* wT = (float*)(ws + 19996672);    // 884 KB
  float* xs = (float*)(ws + 20881408);    // 4.19 MB
  float* xc = (float*)(ws + 25075712);    // 4.19 MB
  float* t1 = (float*)(ws + 29270016);    // 4.19 MB
  float* t2 = (float*)(ws + 33464320);    // 4.19 MB (total 37.7 MB)

  k_wt<<<96, 256, 0, stream>>>((const float*)d_in[9], (const float*)d_in[11],
                               (const float*)d_in[15], (const float*)d_in[17],
                               (const float*)d_in[21], (const float*)d_in[23], wT);
  k_stats<<<9216, 256, 0, stream>>>(corr, st_scl, st_shf);
  k_refscore<<<2048, 256, 0, stream>>>(corr, st_scl, st_shf, rs);
  k_topk<<<256, 256, 0, stream>>>(rs, topidx);
  k_gather<<<4608, 256, 0, stream>>>(corr, st_scl, st_shf, topidx, vbuf);
  k_mlp3<<<256, 256, 0, stream>>>(vbuf, w1s, b1s, w2s, b2s, w1c, b1c, w2c, b2c,
                                  xs, xc);
  // scale head -> scales
  k_conv64T<true><<<512, 256, 0, stream>>>(xs, wT + 0 * 36864, (const float*)d_in[10], t1);
  k_conv64T<true><<<512, 256, 0, stream>>>(t1, wT + 1 * 36864, (const float*)d_in[12], t2);
  k_convS<1><<<256, 256, 0, stream>>>(t2, (const float*)d_in[13], (const float*)d_in[14], scales);
  // offset head -> offsets
  k_conv64T<true><<<512, 256, 0, stream>>>(xc, wT + 2 * 36864, (const float*)d_in[16], t1);
  k_conv64T<true><<<512, 256, 0, stream>>>(t1, wT + 3 * 36864, (const float*)d_in[18], t2);
  k_convS<2><<<256, 256, 0, stream>>>(t2, (const float*)d_in[19], (const float*)d_in[20], offsets);
  // score head -> scores
  k_conv64T<true><<<512, 256, 0, stream>>>(xc, wT + 4 * 36864, (const float*)d_in[22], t1);
  k_conv64T<true><<<512, 256, 0, stream>>>(t1, wT + 5 * 36864, (const float*)d_in[24], t2);
  k_convS<1><<<256, 256, 0, stream>>>(t2, (const float*)d_in[25], (const float*)d_in[26], scores);

  k_final<<<4, 256, 0, stream>>>(scores, scales, offsets, pos, sclo);
}

// Round 6
// 715.203 us; speedup vs baseline: 1.4013x; 1.1804x over previous
//
#include <hip/hip_runtime.h>

#define HW 4096

// ---------------- kernel A: per-(q,r,ns,c) instance-norm stats ----------------
__global__ __launch_bounds__(256) void k_stats(const float* __restrict__ corr,
                                               float* __restrict__ scl,
                                               float* __restrict__ shf) {
  int g = blockIdx.x;  // 0..9215  linear over [q][r][ns][c]
  const float4* p = (const float4*)(corr + (size_t)g * HW);
  int t = threadIdx.x;
  float s = 0.f, s2 = 0.f;
#pragma unroll
  for (int i = 0; i < 4; i++) {
    float4 v = p[t + i * 256];
    s += v.x + v.y + v.z + v.w;
    s2 += v.x * v.x + v.y * v.y + v.z * v.z + v.w * v.w;
  }
#pragma unroll
  for (int o = 32; o > 0; o >>= 1) {
    s += __shfl_down(s, o, 64);
    s2 += __shfl_down(s2, o, 64);
  }
  __shared__ float ls[4], ls2[4];
  int wid = t >> 6;
  if ((t & 63) == 0) { ls[wid] = s; ls2[wid] = s2; }
  __syncthreads();
  if (t == 0) {
    float S = ls[0] + ls[1] + ls[2] + ls[3];
    float S2 = ls2[0] + ls2[1] + ls2[2] + ls2[3];
    float m = S * (1.f / HW);
    float var = S2 * (1.f / HW) - m * m;
    float r = rsqrtf(var + 1e-5f);
    scl[g] = r;
    shf[g] = -m * r;
  }
}

// ------- weight transpose for big convs: [oc][ic][9] -> [ic*9+j][oc] -------
__global__ __launch_bounds__(256) void k_wt(const float* __restrict__ p0,
                                            const float* __restrict__ p1,
                                            const float* __restrict__ p2,
                                            const float* __restrict__ p3,
                                            const float* __restrict__ p4,
                                            const float* __restrict__ p5,
                                            float* __restrict__ wT) {
  int b = blockIdx.x;  // 96 = 6 arrays x 16 chunks
  int arr = b >> 4;
  int chunk = b & 15;
  const float* src = (arr == 0) ? p0
                     : (arr == 1) ? p1
                     : (arr == 2) ? p2
                     : (arr == 3) ? p3
                     : (arr == 4) ? p4 : p5;
  float* dst = wT + arr * 36864;
  int t = threadIdx.x;
#pragma unroll
  for (int i = 0; i < 9; i++) {
    int e = chunk * 2304 + i * 256 + t;  // 0..36863
    int oc = e / 576;
    int rem = e - oc * 576;  // ic*9+j
    dst[rem * 64 + oc] = src[e];
  }
}

// ------- MLP weight transpose: pack w1s[64][72],w2s[64][64],w1c[64][12],
// w2c[64][64] into wm as [c][64] each at offsets 0, 4608, 8704, 9472 -------
__global__ __launch_bounds__(256) void k_wtm(const float* __restrict__ w1s,
                                             const float* __restrict__ w2s,
                                             const float* __restrict__ w1c,
                                             const float* __restrict__ w2c,
                                             float* __restrict__ wm) {
  int i = blockIdx.x * 256 + threadIdx.x;  // grid 53 covers 13568
  if (i < 4608) {
    int c = i >> 6, o = i & 63;
    wm[i] = w1s[o * 72 + c];
  } else if (i < 8704) {
    int j = i - 4608;
    int c = j >> 6, o = j & 63;
    wm[i] = w2s[o * 64 + c];
  } else if (i < 9472) {
    int j = i - 8704;
    int c = j >> 6, o = j & 63;
    wm[i] = w1c[o * 12 + c];
  } else if (i < 13568) {
    int j = i - 9472;
    int c = j >> 6, o = j & 63;
    wm[i] = w2c[o * 64 + c];
  }
}

// ---------------- kernel B: ref_score -> rs[(q*32+r)*4+ns][px] ----------------
__global__ __launch_bounds__(256) void k_refscore(const float* __restrict__ corr,
                                                  const float* __restrict__ scl,
                                                  const float* __restrict__ shf,
                                                  float* __restrict__ rs) {
  int b = blockIdx.x;     // 2048
  int grp = b >> 2;       // 0..511
  int i4 = (b & 3) * 256 + threadIdx.x;  // float4 index 0..1023
  const float* base = corr + (size_t)grp * 18 * HW;
  float4 acc = make_float4(0.f, 0.f, 0.f, 0.f);
  float sh = 0.f;
#pragma unroll
  for (int c = 0; c < 18; c++) {
    float s = scl[grp * 18 + c];
    sh += shf[grp * 18 + c];
    float4 v = ((const float4*)(base + c * HW))[i4];
    acc.x += v.x * s; acc.y += v.y * s; acc.z += v.z * s; acc.w += v.w * s;
  }
  const float inv = 1.f / 18.f;
  float4 o;
  o.x = (acc.x + sh) * inv; o.y = (acc.y + sh) * inv;
  o.z = (acc.z + sh) * inv; o.w = (acc.w + sh) * inv;
  ((float4*)(rs + (size_t)grp * HW))[i4] = o;
}

// ---------------- kernel C: top-4 of 32, LDS-staged ----------------
__global__ __launch_bounds__(256) void k_topk(const float* __restrict__ rs,
                                              int* __restrict__ topidx) {
  __shared__ float st[32 * 256];  // 32 KB
  int b = blockIdx.x;             // 256 = q*4ns*16pxc
  int pxc = b & 15;
  int ns = (b >> 4) & 3;
  int q = b >> 6;
  int t = threadIdx.x;
  int pxb = pxc * 256;
#pragma unroll 8
  for (int r = 0; r < 32; r++)
    st[r * 256 + t] = rs[((q * 32 + r) * 4 + ns) * HW + pxb + t];
  __syncthreads();
  float v[32];
#pragma unroll
  for (int r = 0; r < 32; r++) v[r] = st[r * 256 + t];
  unsigned mask = 0;
  int sel[4];
#pragma unroll
  for (int k = 0; k < 4; k++) {
    float best = -3.4e38f;
    int bi = 0;
#pragma unroll
    for (int r = 0; r < 32; r++) {
      bool take = (!(mask & (1u << r))) && (v[r] > best);
      best = take ? v[r] : best;
      bi = take ? r : bi;
    }
    sel[k] = bi;
    mask |= (1u << bi);
  }
  ((int4*)topidx)[(q * 4 + ns) * HW + pxb + t] =
      make_int4(sel[0], sel[1], sel[2], sel[3]);
}

// -------- kernel D1: high-occupancy streaming gather+norm -> vbuf ----------
__global__ __launch_bounds__(256) void k_gather(const float* __restrict__ corr,
                                                const float* __restrict__ scl,
                                                const float* __restrict__ shf,
                                                const int* __restrict__ topidx,
                                                float* __restrict__ vbuf) {
  __shared__ float ls[32], lsh[32];
  int b = blockIdx.x;  // 4608 = q x pxc x ns x c
  int c = b % 18;
  int rest = b / 18;
  int ns = rest & 3;
  int pxc = (rest >> 2) & 15;
  int q = rest >> 6;
  int t = threadIdx.x;
  int px = pxc * 256 + t;

  if (t < 32) {
    int g = q * 2304 + t * 72 + ns * 18 + c;
    ls[t] = scl[g];
    lsh[t] = shf[g];
  }
  int4 ti = ((const int4*)topidx)[(q * 4 + ns) * HW + px];
  int rk0 = ti.x, rk1 = ti.y, rk2 = ti.z, rk3 = ti.w;
  __syncthreads();

  const float* base = corr + (size_t)(((q * 32) * 4 + ns) * 18 + c) * HW + px;
  float v0 = 0.f, v1 = 0.f, v2 = 0.f, v3 = 0.f;
#pragma unroll
  for (int r = 0; r < 32; r++) {
    float x = base[(size_t)r * 72 * HW];
    v0 = (rk0 == r) ? x : v0;
    v1 = (rk1 == r) ? x : v1;
    v2 = (rk2 == r) ? x : v2;
    v3 = (rk3 == r) ? x : v3;
  }
  v0 = v0 * ls[rk0] + lsh[rk0];
  v1 = v1 * ls[rk1] + lsh[rk1];
  v2 = v2 * ls[rk2] + lsh[rk2];
  v3 = v3 * ls[rk3] + lsh[rk3];
  size_t ob = (size_t)((q * 4 + ns) * 72 + c) * HW + px;
  vbuf[ob] = v0;
  vbuf[ob + 18 * HW] = v1;
  vbuf[ob + 36 * HW] = v2;
  vbuf[ob + 54 * HW] = v3;
}

// ---- kernel D2a: scale-path MLP, transposed weights, 64 indep acc ----
// grid 256 = q(4) x pxc(64); block 256 = ns-wave(4) x 64 px
__global__ __launch_bounds__(256) void k_mlps(const float* __restrict__ vbuf,
                                              const float* __restrict__ w1T,
                                              const float* __restrict__ b1,
                                              const float* __restrict__ w2T,
                                              const float* __restrict__ b2,
                                              float* __restrict__ xs) {
  __shared__ float red8[8 * 256];
  int blk = blockIdx.x;
  int q = blk >> 6, pxc = blk & 63;
  int t = threadIdx.x;
  int ns = t >> 6;  // wave-uniform
  int lane = t & 63;
  int px = pxc * 64 + lane;

  float v[72];
  const float* vb = vbuf + (size_t)((q * 4 + ns) * 72) * HW + px;
#pragma unroll
  for (int j = 0; j < 72; j++) v[j] = vb[(size_t)j * HW];

  float h[64];
#pragma unroll
  for (int o = 0; o < 64; o++) h[o] = b1[o];
#pragma unroll 4
  for (int c = 0; c < 72; c++) {
    float x = v[c];
    const float* wr = w1T + c * 64;  // contiguous 256B -> s_load_dwordx16 x4
#pragma unroll
    for (int o = 0; o < 64; o++) h[o] = fmaf(wr[o], x, h[o]);
  }
#pragma unroll
  for (int o = 0; o < 64; o++) h[o] = fmaxf(h[o], 0.f);
  float a[64];
#pragma unroll
  for (int o = 0; o < 64; o++) a[o] = b2[o];
#pragma unroll 4
  for (int c = 0; c < 64; c++) {
    float x = h[c];
    const float* wr = w2T + c * 64;
#pragma unroll
    for (int o = 0; o < 64; o++) a[o] = fmaf(wr[o], x, a[o]);
  }
  // ns-max across the 4 waves, 8 outputs per round
#pragma unroll
  for (int og = 0; og < 8; og++) {
#pragma unroll
    for (int j = 0; j < 8; j++) red8[j * 256 + t] = a[og * 8 + j];
    __syncthreads();
#pragma unroll
    for (int jj = 0; jj < 2; jj++) {
      int j2 = ns * 2 + jj;
      float m = red8[j2 * 256 + lane];
#pragma unroll
      for (int n2 = 1; n2 < 4; n2++)
        m = fmaxf(m, red8[j2 * 256 + n2 * 64 + lane]);
      xs[(size_t)(q * 64 + og * 8 + j2) * HW + px] = m;
    }
    __syncthreads();
  }
}

// ---- kernel D2b: score-path MLP (level-mean input), transposed weights ----
__global__ __launch_bounds__(256) void k_mlpc(const float* __restrict__ vbuf,
                                              const float* __restrict__ w1T,
                                              const float* __restrict__ b1,
                                              const float* __restrict__ w2T,
                                              const float* __restrict__ b2,
                                              float* __restrict__ xc) {
  __shared__ float red8[8 * 256];
  int blk = blockIdx.x;
  int q = blk >> 6, pxc = blk & 63;
  int t = threadIdx.x;
  int ns = t >> 6;
  int lane = t & 63;
  int px = pxc * 64 + lane;

  float xsc[12];
  const float* vb = vbuf + (size_t)((q * 4 + ns) * 72) * HW + px;
#pragma unroll
  for (int k = 0; k < 4; k++)
#pragma unroll
    for (int l = 0; l < 3; l++) {
      float s = 0.f;
#pragma unroll
      for (int j = 0; j < 6; j++)
        s += vb[(size_t)(k * 18 + l * 6 + j) * HW];
      xsc[k * 3 + l] = s * (1.f / 6.f);
    }
  float h[64];
#pragma unroll
  for (int o = 0; o < 64; o++) h[o] = b1[o];
#pragma unroll 4
  for (int c = 0; c < 12; c++) {
    float x = xsc[c];
    const float* wr = w1T + c * 64;
#pragma unroll
    for (int o = 0; o < 64; o++) h[o] = fmaf(wr[o], x, h[o]);
  }
#pragma unroll
  for (int o = 0; o < 64; o++) h[o] = fmaxf(h[o], 0.f);
  float a[64];
#pragma unroll
  for (int o = 0; o < 64; o++) a[o] = b2[o];
#pragma unroll 4
  for (int c = 0; c < 64; c++) {
    float x = h[c];
    const float* wr = w2T + c * 64;
#pragma unroll
    for (int o = 0; o < 64; o++) a[o] = fmaf(wr[o], x, a[o]);
  }
#pragma unroll
  for (int og = 0; og < 8; og++) {
#pragma unroll
    for (int j = 0; j < 8; j++) red8[j * 256 + t] = a[og * 8 + j];
    __syncthreads();
#pragma unroll
    for (int jj = 0; jj < 2; jj++) {
      int j2 = ns * 2 + jj;
      float m = red8[j2 * 256 + lane];
#pragma unroll
      for (int n2 = 1; n2 < 4; n2++)
        m = fmaxf(m, red8[j2 * 256 + n2 * 64 + lane]);
      xc[(size_t)(q * 64 + og * 8 + j2) * HW + px] = m;
    }
    __syncthreads();
  }
}

// ---- merged big 3x3 conv layer: 3 heads x 8 og x 64 tiles = 1536 blocks ----
// b%8 depends only on tile -> og/head siblings share XCD -> L2-hot staging.
template <bool RELU>
__global__ __launch_bounds__(256) void k_conv3h(
    const float* __restrict__ in0, const float* __restrict__ in1,
    const float* __restrict__ in2, const float* __restrict__ w0,
    const float* __restrict__ w1, const float* __restrict__ w2,
    const float* __restrict__ bb0, const float* __restrict__ bb1,
    const float* __restrict__ bb2, float* __restrict__ o0,
    float* __restrict__ o1, float* __restrict__ o2) {
  __shared__ float tile[16 * 6 * 66];  // 25.3 KB -> 6 blocks/CU
  int b = blockIdx.x;                  // 1536 = (og*3+head)*64 + q*16 + rt
  int hi = b >> 6;                     // og*3 + head
  int og = hi / 3;
  int head = hi - og * 3;
  int tl = b & 63;
  int q = tl >> 4;
  int rt = tl & 15;
  const float* in = head == 0 ? in0 : head == 1 ? in1 : in2;
  const float* wT = head == 0 ? w0 : head == 1 ? w1 : w2;
  const float* bb = head == 0 ? bb0 : head == 1 ? bb1 : bb2;
  float* outp = head == 0 ? o0 : head == 1 ? o1 : o2;

  int t = threadIdx.x;
  int w = t & 63;
  int wr = t >> 6;  // wave-uniform
  float acc[8] = {0.f, 0.f, 0.f, 0.f, 0.f, 0.f, 0.f, 0.f};
  if (t < 96) { tile[t * 66] = 0.f; tile[t * 66 + 65] = 0.f; }
  const float* inq = in + (size_t)q * 64 * HW;
  for (int icc = 0; icc < 4; icc++) {
    __syncthreads();
#pragma unroll
    for (int p = 0; p < 24; p++) {
      int idx = p * 4 + wr;  // ch*6 + r, 0..95 (uniform)
      int r = idx % 6;
      int ch = idx / 6;
      int grow = rt * 4 + r - 1;
      float val = 0.f;
      if (grow >= 0 && grow < 64)
        val = inq[(size_t)(icc * 16 + ch) * HW + grow * 64 + w];
      tile[idx * 66 + 1 + w] = val;
    }
    __syncthreads();
#pragma unroll 2
    for (int ic = 0; ic < 16; ic++) {
      float x[9];
#pragma unroll
      for (int dr = 0; dr < 3; dr++)
#pragma unroll
        for (int dc = 0; dc < 3; dc++)
          x[dr * 3 + dc] = tile[(ic * 6 + wr + dr) * 66 + w + dc];
      const float* wb = wT + (size_t)(icc * 16 + ic) * 9 * 64 + og * 8;
#pragma unroll
      for (int j = 0; j < 9; j++) {
        const float* wv = wb + j * 64;
#pragma unroll
        for (int o = 0; o < 8; o++) acc[o] += wv[o] * x[j];
      }
    }
  }
  int orow = rt * 4 + wr;
#pragma unroll
  for (int o = 0; o < 8; o++) {
    float rz = acc[o] + bb[og * 8 + o];
    if (RELU) rz = fmaxf(rz, 0.f);
    outp[((size_t)q * 64 + og * 8 + o) * HW + orow * 64 + w] = rz;
  }
}

// ---- merged small 3x3 conv (heads: OC=1,2,1), 1-row blocks ----
__global__ __launch_bounds__(256) void k_convSh(
    const float* __restrict__ in0, const float* __restrict__ in1,
    const float* __restrict__ in2, const float* __restrict__ wt0,
    const float* __restrict__ wt1, const float* __restrict__ wt2,
    const float* __restrict__ bb0, const float* __restrict__ bb1,
    const float* __restrict__ bb2, float* __restrict__ o0,
    float* __restrict__ o1, float* __restrict__ o2) {
  __shared__ float tile[64 * 3 * 66];  // 50.7 KB
  __shared__ float red[4 * 2 * 64];
  int b = blockIdx.x;  // 768 = head*256 + q*64 + row
  int head = b >> 8;
  int q = (b >> 6) & 3;
  int row = b & 63;
  const float* in = head == 0 ? in0 : head == 1 ? in1 : in2;
  const float* wt = head == 0 ? wt0 : head == 1 ? wt1 : wt2;
  const float* bb = head == 0 ? bb0 : head == 1 ? bb1 : bb2;
  float* outp = head == 0 ? o0 : head == 1 ? o1 : o2;
  int noc = (head == 1) ? 2 : 1;

  int t = threadIdx.x;
  int w = t & 63;
  int sub = t >> 6;  // ic quarter (wave-uniform)
  if (t < 192) { tile[t * 66] = 0.f; tile[t * 66 + 65] = 0.f; }
  __syncthreads();
  const float* inq = in + (size_t)q * 64 * HW;
#pragma unroll
  for (int i = 0; i < 48; i++) {
    int idx = i * 4 + sub;  // ic*3 + r (uniform)
    int ic = idx / 3;
    int r = idx - ic * 3;
    int grow = row + r - 1;
    float val = 0.f;
    if (grow >= 0 && grow < 64) val = inq[(size_t)ic * HW + grow * 64 + w];
    tile[idx * 66 + 1 + w] = val;
  }
  __syncthreads();
  float acc0 = 0.f, acc1 = 0.f;
#pragma unroll 4
  for (int i = 0; i < 16; i++) {
    int ic = sub * 16 + i;
    float x[9];
#pragma unroll
    for (int dr = 0; dr < 3; dr++)
#pragma unroll
      for (int dc = 0; dc < 3; dc++)
        x[dr * 3 + dc] = tile[(ic * 3 + dr) * 66 + w + dc];
    const float* wb = wt + (size_t)ic * 9;
#pragma unroll
    for (int j = 0; j < 9; j++) acc0 += wb[j] * x[j];
    if (noc == 2) {
      const float* wb1 = wt + 576 + (size_t)ic * 9;
#pragma unroll
      for (int j = 0; j < 9; j++) acc1 += wb1[j] * x[j];
    }
  }
  red[(sub * 2 + 0) * 64 + w] = acc0;
  if (noc == 2) red[(sub * 2 + 1) * 64 + w] = acc1;
  __syncthreads();
  if (t < 128) {
    int o = t >> 6;
    if (o < noc) {
      float s = red[(0 * 2 + o) * 64 + w] + red[(1 * 2 + o) * 64 + w] +
                red[(2 * 2 + o) * 64 + w] + red[(3 * 2 + o) * 64 + w] + bb[o];
      outp[((size_t)q * noc + o) * HW + row * 64 + w] = s;
    }
  }
}

// ---------------- final: argmax + pos/scl ----------------
__global__ __launch_bounds__(256) void k_final(const float* __restrict__ scores,
                                               const float* __restrict__ scales,
                                               const float* __restrict__ offsets,
                                               float* __restrict__ pos,
                                               float* __restrict__ sclo) {
  int q = blockIdx.x, t = threadIdx.x;
  float best = -3.4e38f;
  int bi = 1 << 30;
  for (int i = t; i < HW; i += 256) {
    float v = scores[q * HW + i];
    if (v > best) { best = v; bi = i; }
  }
  __shared__ float bv[256];
  __shared__ int bix[256];
  bv[t] = best;
  bix[t] = bi;
  __syncthreads();
  for (int s = 128; s > 0; s >>= 1) {
    if (t < s) {
      if (bv[t + s] > bv[t] || (bv[t + s] == bv[t] && bix[t + s] < bix[t])) {
        bv[t] = bv[t + s];
        bix[t] = bix[t + s];
      }
    }
    __syncthreads();
  }
  if (t == 0) {
    int sid = bix[0];
    int sy = sid >> 6, sx = sid & 63;
    float o0 = offsets[(q * 2 + 0) * HW + sid];
    float o1 = offsets[(q * 2 + 1) * HW + sid];
    pos[q * 2 + 0] = ((float)sx + o0 + 0.5f) * 8.f - 0.5f;
    pos[q * 2 + 1] = ((float)sy + o1 + 0.5f) * 8.f - 0.5f;
    sclo[q] = exp2f(scales[q * HW + sid]);
  }
}

extern "C" void kernel_launch(void* const* d_in, const int* in_sizes, int n_in,
                              void* d_out, int out_size, void* d_ws, size_t ws_size,
                              hipStream_t stream) {
  const float* corr = (const float*)d_in[0];
  const float* w1s = (const float*)d_in[1];
  const float* b1s = (const float*)d_in[2];
  const float* w2s = (const float*)d_in[3];
  const float* b2s = (const float*)d_in[4];
  const float* w1c = (const float*)d_in[5];
  const float* b1c = (const float*)d_in[6];
  const float* w2c = (const float*)d_in[7];
  const float* b2c = (const float*)d_in[8];

  float* out = (float*)d_out;
  float* pos = out;                   // (4,2)
  float* sclo = out + 8;              // (4,)
  float* scores = out + 12;           // (4,1,64,64)
  float* scales = out + 12 + 16384;   // (4,1,64,64)
  float* offsets = out + 12 + 32768;  // (4,2,64,64)

  char* ws = (char*)d_ws;
  float* st_scl = (float*)(ws + 0);       // 36 KB
  float* st_shf = (float*)(ws + 36864);   // 36 KB
  int* topidx = (int*)(ws + 73728);       // 1 MB
  float* rs = (float*)(ws + 1122304);     // 8.39 MB (dead after k_topk)
  float* vbuf = rs;                       // 18.87 MB, overlaps rs (ok)
  float* wT = (float*)(ws + 19996672);    // 884 KB (big-conv transposed w)
  float* wmT = (float*)(ws + 20881408);   // 54 KB (MLP transposed w)
  float* xs = (float*)(ws + 20971520);    // 4.19 MB
  float* xc = (float*)(ws + 25165824);    // 4.19 MB  (total 29.4 MB)
  // t1/t2 reuse dead regions (stream-ordered):
  float* t1s = vbuf;                         // vbuf dead after MLPs
  float* t1o = (float*)((char*)vbuf + 4194304);
  float* t1c = (float*)((char*)vbuf + 8388608);
  float* t2c = (float*)((char*)vbuf + 12582912);
  float* t2s = xs;                           // xs dead after conv layer 1
  float* t2o = xc;                           // xc dead after conv layer 1

  k_wt<<<96, 256, 0, stream>>>((const float*)d_in[9], (const float*)d_in[11],
                               (const float*)d_in[15], (const float*)d_in[17],
                               (const float*)d_in[21], (const float*)d_in[23], wT);
  k_wtm<<<53, 256, 0, stream>>>(w1s, w2s, w1c, w2c, wmT);
  k_stats<<<9216, 256, 0, stream>>>(corr, st_scl, st_shf);
  k_refscore<<<2048, 256, 0, stream>>>(corr, st_scl, st_shf, rs);
  k_topk<<<256, 256, 0, stream>>>(rs, topidx);
  k_gather<<<4608, 256, 0, stream>>>(corr, st_scl, st_shf, topidx, vbuf);
  k_mlps<<<256, 256, 0, stream>>>(vbuf, wmT, b1s, wmT + 4608, b2s, xs);
  k_mlpc<<<256, 256, 0, stream>>>(vbuf, wmT + 8704, b1c, wmT + 9472, b2c, xc);
  // conv layer 1 (all heads): xs->t1s, xc->t1o, xc->t1c
  k_conv3h<true><<<1536, 256, 0, stream>>>(
      xs, xc, xc, wT, wT + 2 * 36864, wT + 4 * 36864,
      (const float*)d_in[10], (const float*)d_in[16], (const float*)d_in[22],
      t1s, t1o, t1c);
  // conv layer 2 (all heads): t1*->t2*
  k_conv3h<true><<<1536, 256, 0, stream>>>(
      t1s, t1o, t1c, wT + 1 * 36864, wT + 3 * 36864, wT + 5 * 36864,
      (const float*)d_in[12], (const float*)d_in[18], (const float*)d_in[24],
      t2s, t2o, t2c);
  // conv layer 3 (all heads): t2* -> scales/offsets/scores
  k_convSh<<<768, 256, 0, stream>>>(
      t2s, t2o, t2c, (const float*)d_in[13], (const float*)d_in[19],
      (const float*)d_in[25], (const float*)d_in[14], (const float*)d_in[20],
      (const float*)d_in[26], scales, offsets, scores);

  k_final<<<4, 256, 0, stream>>>(scores, scales, offsets, pos, sclo);
}

// Round 7
// 550.558 us; speedup vs baseline: 1.8204x; 1.2991x over previous
//
#include <hip/hip_runtime.h>

#define HW 4096

// ---------------- kernel A: per-(q,r,ns,c) instance-norm stats ----------------
__global__ __launch_bounds__(256) void k_stats(const float* __restrict__ corr,
                                               float* __restrict__ scl,
                                               float* __restrict__ shf) {
  int g = blockIdx.x;  // 0..9215  linear over [q][r][ns][c]
  const float4* p = (const float4*)(corr + (size_t)g * HW);
  int t = threadIdx.x;
  float s = 0.f, s2 = 0.f;
#pragma unroll
  for (int i = 0; i < 4; i++) {
    float4 v = p[t + i * 256];
    s += v.x + v.y + v.z + v.w;
    s2 += v.x * v.x + v.y * v.y + v.z * v.z + v.w * v.w;
  }
#pragma unroll
  for (int o = 32; o > 0; o >>= 1) {
    s += __shfl_down(s, o, 64);
    s2 += __shfl_down(s2, o, 64);
  }
  __shared__ float ls[4], ls2[4];
  int wid = t >> 6;
  if ((t & 63) == 0) { ls[wid] = s; ls2[wid] = s2; }
  __syncthreads();
  if (t == 0) {
    float S = ls[0] + ls[1] + ls[2] + ls[3];
    float S2 = ls2[0] + ls2[1] + ls2[2] + ls2[3];
    float m = S * (1.f / HW);
    float var = S2 * (1.f / HW) - m * m;
    float r = rsqrtf(var + 1e-5f);
    scl[g] = r;
    shf[g] = -m * r;
  }
}

// ------- weight transposes (conv: [oc][ic][9]->[ic*9+j][oc]; MLP: [o][c]->[c][o])
__global__ __launch_bounds__(256) void k_wx(
    const float* __restrict__ p0, const float* __restrict__ p1,
    const float* __restrict__ p2, const float* __restrict__ p3,
    const float* __restrict__ p4, const float* __restrict__ p5,
    float* __restrict__ wT, const float* __restrict__ w1s,
    const float* __restrict__ w2s, const float* __restrict__ w1c,
    const float* __restrict__ w2c, float* __restrict__ wm) {
  int b = blockIdx.x;  // 96 conv chunks + 53 mlp chunks = 149
  int t = threadIdx.x;
  if (b < 96) {
    int arr = b >> 4;
    int chunk = b & 15;
    const float* src = (arr == 0) ? p0
                       : (arr == 1) ? p1
                       : (arr == 2) ? p2
                       : (arr == 3) ? p3
                       : (arr == 4) ? p4 : p5;
    float* dst = wT + arr * 36864;
#pragma unroll
    for (int i = 0; i < 9; i++) {
      int e = chunk * 2304 + i * 256 + t;  // 0..36863
      int oc = e / 576;
      int rem = e - oc * 576;  // ic*9+j
      dst[rem * 64 + oc] = src[e];
    }
  } else {
    int i = (b - 96) * 256 + t;
    if (i < 4608) {
      int c = i >> 6, o = i & 63;
      wm[i] = w1s[o * 72 + c];
    } else if (i < 8704) {
      int j = i - 4608;
      int c = j >> 6, o = j & 63;
      wm[i] = w2s[o * 64 + c];
    } else if (i < 9472) {
      int j = i - 8704;
      int c = j >> 6, o = j & 63;
      wm[i] = w1c[o * 12 + c];
    } else if (i < 13568) {
      int j = i - 9472;
      int c = j >> 6, o = j & 63;
      wm[i] = w2c[o * 64 + c];
    }
  }
}

// ---------------- kernel B: ref_score -> rs[(q*32+r)*4+ns][px] ----------------
__global__ __launch_bounds__(256) void k_refscore(const float* __restrict__ corr,
                                                  const float* __restrict__ scl,
                                                  const float* __restrict__ shf,
                                                  float* __restrict__ rs) {
  int b = blockIdx.x;     // 2048
  int grp = b >> 2;       // 0..511
  int i4 = (b & 3) * 256 + threadIdx.x;  // float4 index 0..1023
  const float* base = corr + (size_t)grp * 18 * HW;
  float4 acc = make_float4(0.f, 0.f, 0.f, 0.f);
  float sh = 0.f;
#pragma unroll
  for (int c = 0; c < 18; c++) {
    float s = scl[grp * 18 + c];
    sh += shf[grp * 18 + c];
    float4 v = ((const float4*)(base + c * HW))[i4];
    acc.x += v.x * s; acc.y += v.y * s; acc.z += v.z * s; acc.w += v.w * s;
  }
  const float inv = 1.f / 18.f;
  float4 o;
  o.x = (acc.x + sh) * inv; o.y = (acc.y + sh) * inv;
  o.z = (acc.z + sh) * inv; o.w = (acc.w + sh) * inv;
  ((float4*)(rs + (size_t)grp * HW))[i4] = o;
}

// ---------------- kernel C: top-4 of 32, LDS-staged ----------------
__global__ __launch_bounds__(256) void k_topk(const float* __restrict__ rs,
                                              int* __restrict__ topidx) {
  __shared__ float st[32 * 256];  // 32 KB
  int b = blockIdx.x;             // 256 = q*4ns*16pxc
  int pxc = b & 15;
  int ns = (b >> 4) & 3;
  int q = b >> 6;
  int t = threadIdx.x;
  int pxb = pxc * 256;
#pragma unroll 8
  for (int r = 0; r < 32; r++)
    st[r * 256 + t] = rs[((q * 32 + r) * 4 + ns) * HW + pxb + t];
  __syncthreads();
  float v[32];
#pragma unroll
  for (int r = 0; r < 32; r++) v[r] = st[r * 256 + t];
  unsigned mask = 0;
  int sel[4];
#pragma unroll
  for (int k = 0; k < 4; k++) {
    float best = -3.4e38f;
    int bi = 0;
#pragma unroll
    for (int r = 0; r < 32; r++) {
      bool take = (!(mask & (1u << r))) && (v[r] > best);
      best = take ? v[r] : best;
      bi = take ? r : bi;
    }
    sel[k] = bi;
    mask |= (1u << bi);
  }
  ((int4*)topidx)[(q * 4 + ns) * HW + pxb + t] =
      make_int4(sel[0], sel[1], sel[2], sel[3]);
}

// -------- kernel D1: high-occupancy streaming gather+norm -> vbuf ----------
__global__ __launch_bounds__(256) void k_gather(const float* __restrict__ corr,
                                                const float* __restrict__ scl,
                                                const float* __restrict__ shf,
                                                const int* __restrict__ topidx,
                                                float* __restrict__ vbuf) {
  __shared__ float ls[32], lsh[32];
  int b = blockIdx.x;  // 4608 = q x pxc x ns x c
  int c = b % 18;
  int rest = b / 18;
  int ns = rest & 3;
  int pxc = (rest >> 2) & 15;
  int q = rest >> 6;
  int t = threadIdx.x;
  int px = pxc * 256 + t;

  if (t < 32) {
    int g = q * 2304 + t * 72 + ns * 18 + c;
    ls[t] = scl[g];
    lsh[t] = shf[g];
  }
  int4 ti = ((const int4*)topidx)[(q * 4 + ns) * HW + px];
  int rk0 = ti.x, rk1 = ti.y, rk2 = ti.z, rk3 = ti.w;
  __syncthreads();

  const float* base = corr + (size_t)(((q * 32) * 4 + ns) * 18 + c) * HW + px;
  float v0 = 0.f, v1 = 0.f, v2 = 0.f, v3 = 0.f;
#pragma unroll
  for (int r = 0; r < 32; r++) {
    float x = base[(size_t)r * 72 * HW];
    v0 = (rk0 == r) ? x : v0;
    v1 = (rk1 == r) ? x : v1;
    v2 = (rk2 == r) ? x : v2;
    v3 = (rk3 == r) ? x : v3;
  }
  v0 = v0 * ls[rk0] + lsh[rk0];
  v1 = v1 * ls[rk1] + lsh[rk1];
  v2 = v2 * ls[rk2] + lsh[rk2];
  v3 = v3 * ls[rk3] + lsh[rk3];
  size_t ob = (size_t)((q * 4 + ns) * 72 + c) * HW + px;
  vbuf[ob] = v0;
  vbuf[ob + 18 * HW] = v1;
  vbuf[ob + 36 * HW] = v2;
  vbuf[ob + 54 * HW] = v3;
}

// ---- kernel D2a: scale-path MLP, transposed weights, 64 indep acc ----
__global__ __launch_bounds__(256) void k_mlps(const float* __restrict__ vbuf,
                                              const float* __restrict__ w1T,
                                              const float* __restrict__ b1,
                                              const float* __restrict__ w2T,
                                              const float* __restrict__ b2,
                                              float* __restrict__ xs) {
  __shared__ float red8[8 * 256];
  int blk = blockIdx.x;
  int q = blk >> 6, pxc = blk & 63;
  int t = threadIdx.x;
  int ns = t >> 6;  // wave-uniform
  int lane = t & 63;
  int px = pxc * 64 + lane;

  float v[72];
  const float* vb = vbuf + (size_t)((q * 4 + ns) * 72) * HW + px;
#pragma unroll
  for (int j = 0; j < 72; j++) v[j] = vb[(size_t)j * HW];

  float h[64];
#pragma unroll
  for (int o = 0; o < 64; o++) h[o] = b1[o];
#pragma unroll 4
  for (int c = 0; c < 72; c++) {
    float x = v[c];
    const float* wr = w1T + c * 64;
#pragma unroll
    for (int o = 0; o < 64; o++) h[o] = fmaf(wr[o], x, h[o]);
  }
#pragma unroll
  for (int o = 0; o < 64; o++) h[o] = fmaxf(h[o], 0.f);
  float a[64];
#pragma unroll
  for (int o = 0; o < 64; o++) a[o] = b2[o];
#pragma unroll 4
  for (int c = 0; c < 64; c++) {
    float x = h[c];
    const float* wr = w2T + c * 64;
#pragma unroll
    for (int o = 0; o < 64; o++) a[o] = fmaf(wr[o], x, a[o]);
  }
#pragma unroll
  for (int og = 0; og < 8; og++) {
#pragma unroll
    for (int j = 0; j < 8; j++) red8[j * 256 + t] = a[og * 8 + j];
    __syncthreads();
#pragma unroll
    for (int jj = 0; jj < 2; jj++) {
      int j2 = ns * 2 + jj;
      float m = red8[j2 * 256 + lane];
#pragma unroll
      for (int n2 = 1; n2 < 4; n2++)
        m = fmaxf(m, red8[j2 * 256 + n2 * 64 + lane]);
      xs[(size_t)(q * 64 + og * 8 + j2) * HW + px] = m;
    }
    __syncthreads();
  }
}

// ---- kernel D2b: score-path MLP (level-mean input), transposed weights ----
__global__ __launch_bounds__(256) void k_mlpc(const float* __restrict__ vbuf,
                                              const float* __restrict__ w1T,
                                              const float* __restrict__ b1,
                                              const float* __restrict__ w2T,
                                              const float* __restrict__ b2,
                                              float* __restrict__ xc) {
  __shared__ float red8[8 * 256];
  int blk = blockIdx.x;
  int q = blk >> 6, pxc = blk & 63;
  int t = threadIdx.x;
  int ns = t >> 6;
  int lane = t & 63;
  int px = pxc * 64 + lane;

  float xsc[12];
  const float* vb = vbuf + (size_t)((q * 4 + ns) * 72) * HW + px;
#pragma unroll
  for (int k = 0; k < 4; k++)
#pragma unroll
    for (int l = 0; l < 3; l++) {
      float s = 0.f;
#pragma unroll
      for (int j = 0; j < 6; j++)
        s += vb[(size_t)(k * 18 + l * 6 + j) * HW];
      xsc[k * 3 + l] = s * (1.f / 6.f);
    }
  float h[64];
#pragma unroll
  for (int o = 0; o < 64; o++) h[o] = b1[o];
#pragma unroll 4
  for (int c = 0; c < 12; c++) {
    float x = xsc[c];
    const float* wr = w1T + c * 64;
#pragma unroll
    for (int o = 0; o < 64; o++) h[o] = fmaf(wr[o], x, h[o]);
  }
#pragma unroll
  for (int o = 0; o < 64; o++) h[o] = fmaxf(h[o], 0.f);
  float a[64];
#pragma unroll
  for (int o = 0; o < 64; o++) a[o] = b2[o];
#pragma unroll 4
  for (int c = 0; c < 64; c++) {
    float x = h[c];
    const float* wr = w2T + c * 64;
#pragma unroll
    for (int o = 0; o < 64; o++) a[o] = fmaf(wr[o], x, a[o]);
  }
#pragma unroll
  for (int og = 0; og < 8; og++) {
#pragma unroll
    for (int j = 0; j < 8; j++) red8[j * 256 + t] = a[og * 8 + j];
    __syncthreads();
#pragma unroll
    for (int jj = 0; jj < 2; jj++) {
      int j2 = ns * 2 + jj;
      float m = red8[j2 * 256 + lane];
#pragma unroll
      for (int n2 = 1; n2 < 4; n2++)
        m = fmaxf(m, red8[j2 * 256 + n2 * 64 + lane]);
      xc[(size_t)(q * 64 + og * 8 + j2) * HW + px] = m;
    }
    __syncthreads();
  }
}

// ---- merged big 3x3 conv v2: 2 rows x 8 oc per thread, float4 staging ----
// grid 768 = hi(24: og*3+head)*32 + q*8 + rt.  Tile: 8 out rows x 64 cols.
// LDS 16ic x 10 rows x 72 stride (data at col 4..67, pads col 3 & 68) = 46 KB.
template <bool RELU>
__global__ __launch_bounds__(256) void k_conv3h(
    const float* __restrict__ in0, const float* __restrict__ in1,
    const float* __restrict__ in2, const float* __restrict__ w0,
    const float* __restrict__ w1, const float* __restrict__ w2,
    const float* __restrict__ bb0, const float* __restrict__ bb1,
    const float* __restrict__ bb2, float* __restrict__ o0,
    float* __restrict__ o1, float* __restrict__ o2) {
  __shared__ float tile[16 * 10 * 72];  // 46.1 KB -> 3 blocks/CU
  int b = blockIdx.x;
  int hi = b >> 5;  // og*3 + head
  int og = hi / 3;
  int head = hi - og * 3;
  int q = (b >> 3) & 3;
  int rt = b & 7;
  const float* in = head == 0 ? in0 : head == 1 ? in1 : in2;
  const float* wT = head == 0 ? w0 : head == 1 ? w1 : w2;
  const float* bb = head == 0 ? bb0 : head == 1 ? bb1 : bb2;
  float* outp = head == 0 ? o0 : head == 1 ? o1 : o2;

  int t = threadIdx.x;
  int w = t & 63;
  int wr = t >> 6;       // 0..3 (wave-uniform): thread rows 2wr, 2wr+1
  int lane4 = t & 15;    // staging: float4 col
  int rgrp = t >> 4;     // staging: 16 rows/pass
  float acc[2][8];
#pragma unroll
  for (int pr = 0; pr < 2; pr++)
#pragma unroll
    for (int o = 0; o < 8; o++) acc[pr][o] = 0.f;
  const float* inq = in + (size_t)q * 64 * HW;

  for (int icc = 0; icc < 4; icc++) {
    __syncthreads();
    // edge pads (rows 0..159): col 3 (img -1) and col 68 (img 64)
    if (t < 160) { tile[t * 72 + 3] = 0.f; tile[t * 72 + 68] = 0.f; }
    // stage 16 ic x 10 rows x 64 cols as float4
#pragma unroll
    for (int p = 0; p < 10; p++) {
      int idx = p * 16 + rgrp;  // 0..159
      int ch = idx / 10;
      int r = idx - ch * 10;
      int grow = rt * 8 + r - 1;
      float4 val = make_float4(0.f, 0.f, 0.f, 0.f);
      if (grow >= 0 && grow < 64)
        val = *(const float4*)(inq + (size_t)(icc * 16 + ch) * HW + grow * 64 +
                               lane4 * 4);
      *(float4*)(tile + idx * 72 + 4 + lane4 * 4) = val;
    }
    __syncthreads();
#pragma unroll 2
    for (int ic = 0; ic < 16; ic++) {
      // x window: 4 tile rows x 3 cols
      float xv[4][3];
      const float* tb = tile + (ic * 10 + wr * 2) * 72 + w + 3;
#pragma unroll
      for (int rr = 0; rr < 4; rr++)
#pragma unroll
        for (int dc = 0; dc < 3; dc++) xv[rr][dc] = tb[rr * 72 + dc];
      const float* wb = wT + (size_t)(icc * 16 + ic) * 9 * 64 + og * 8;
#pragma unroll
      for (int dr = 0; dr < 3; dr++)
#pragma unroll
        for (int dc = 0; dc < 3; dc++) {
          const float* wv = wb + (dr * 3 + dc) * 64;
#pragma unroll
          for (int o = 0; o < 8; o++) {
            float wj = wv[o];
            acc[0][o] = fmaf(wj, xv[0 + dr][dc], acc[0][o]);
            acc[1][o] = fmaf(wj, xv[1 + dr][dc], acc[1][o]);
          }
        }
    }
  }
#pragma unroll
  for (int pr = 0; pr < 2; pr++) {
    int orow = rt * 8 + wr * 2 + pr;
#pragma unroll
    for (int o = 0; o < 8; o++) {
      float rz = acc[pr][o] + bb[og * 8 + o];
      if (RELU) rz = fmaxf(rz, 0.f);
      outp[((size_t)q * 64 + og * 8 + o) * HW + orow * 64 + w] = rz;
    }
  }
}

// ---- merged small 3x3 conv (heads: OC=1,2,1), 1-row blocks ----
__global__ __launch_bounds__(256) void k_convSh(
    const float* __restrict__ in0, const float* __restrict__ in1,
    const float* __restrict__ in2, const float* __restrict__ wt0,
    const float* __restrict__ wt1, const float* __restrict__ wt2,
    const float* __restrict__ bb0, const float* __restrict__ bb1,
    const float* __restrict__ bb2, float* __restrict__ o0,
    float* __restrict__ o1, float* __restrict__ o2) {
  __shared__ float tile[64 * 3 * 66];  // 50.7 KB
  __shared__ float red[4 * 2 * 64];
  int b = blockIdx.x;  // 768 = head*256 + q*64 + row
  int head = b >> 8;
  int q = (b >> 6) & 3;
  int row = b & 63;
  const float* in = head == 0 ? in0 : head == 1 ? in1 : in2;
  const float* wt = head == 0 ? wt0 : head == 1 ? wt1 : wt2;
  const float* bb = head == 0 ? bb0 : head == 1 ? bb1 : bb2;
  float* outp = head == 0 ? o0 : head == 1 ? o1 : o2;
  int noc = (head == 1) ? 2 : 1;

  int t = threadIdx.x;
  int w = t & 63;
  int sub = t >> 6;
  if (t < 192) { tile[t * 66] = 0.f; tile[t * 66 + 65] = 0.f; }
  __syncthreads();
  const float* inq = in + (size_t)q * 64 * HW;
#pragma unroll
  for (int i = 0; i < 48; i++) {
    int idx = i * 4 + sub;
    int ic = idx / 3;
    int r = idx - ic * 3;
    int grow = row + r - 1;
    float val = 0.f;
    if (grow >= 0 && grow < 64) val = inq[(size_t)ic * HW + grow * 64 + w];
    tile[idx * 66 + 1 + w] = val;
  }
  __syncthreads();
  float acc0 = 0.f, acc1 = 0.f;
#pragma unroll 4
  for (int i = 0; i < 16; i++) {
    int ic = sub * 16 + i;
    float x[9];
#pragma unroll
    for (int dr = 0; dr < 3; dr++)
#pragma unroll
      for (int dc = 0; dc < 3; dc++)
        x[dr * 3 + dc] = tile[(ic * 3 + dr) * 66 + w + dc];
    const float* wb = wt + (size_t)ic * 9;
#pragma unroll
    for (int j = 0; j < 9; j++) acc0 += wb[j] * x[j];
    if (noc == 2) {
      const float* wb1 = wt + 576 + (size_t)ic * 9;
#pragma unroll
      for (int j = 0; j < 9; j++) acc1 += wb1[j] * x[j];
    }
  }
  red[(sub * 2 + 0) * 64 + w] = acc0;
  if (noc == 2) red[(sub * 2 + 1) * 64 + w] = acc1;
  __syncthreads();
  if (t < 128) {
    int o = t >> 6;
    if (o < noc) {
      float s = red[(0 * 2 + o) * 64 + w] + red[(1 * 2 + o) * 64 + w] +
                red[(2 * 2 + o) * 64 + w] + red[(3 * 2 + o) * 64 + w] + bb[o];
      outp[((size_t)q * noc + o) * HW + row * 64 + w] = s;
    }
  }
}

// ---------------- final: argmax + pos/scl ----------------
__global__ __launch_bounds__(256) void k_final(const float* __restrict__ scores,
                                               const float* __restrict__ scales,
                                               const float* __restrict__ offsets,
                                               float* __restrict__ pos,
                                               float* __restrict__ sclo) {
  int q = blockIdx.x, t = threadIdx.x;
  float best = -3.4e38f;
  int bi = 1 << 30;
  for (int i = t; i < HW; i += 256) {
    float v = scores[q * HW + i];
    if (v > best) { best = v; bi = i; }
  }
  __shared__ float bv[256];
  __shared__ int bix[256];
  bv[t] = best;
  bix[t] = bi;
  __syncthreads();
  for (int s = 128; s > 0; s >>= 1) {
    if (t < s) {
      if (bv[t + s] > bv[t] || (bv[t + s] == bv[t] && bix[t + s] < bix[t])) {
        bv[t] = bv[t + s];
        bix[t] = bix[t + s];
      }
    }
    __syncthreads();
  }
  if (t == 0) {
    int sid = bix[0];
    int sy = sid >> 6, sx = sid & 63;
    float o0 = offsets[(q * 2 + 0) * HW + sid];
    float o1 = offsets[(q * 2 + 1) * HW + sid];
    pos[q * 2 + 0] = ((float)sx + o0 + 0.5f) * 8.f - 0.5f;
    pos[q * 2 + 1] = ((float)sy + o1 + 0.5f) * 8.f - 0.5f;
    sclo[q] = exp2f(scales[q * HW + sid]);
  }
}

extern "C" void kernel_launch(void* const* d_in, const int* in_sizes, int n_in,
                              void* d_out, int out_size, void* d_ws, size_t ws_size,
                              hipStream_t stream) {
  const float* corr = (const float*)d_in[0];
  const float* w1s = (const float*)d_in[1];
  const float* b1s = (const float*)d_in[2];
  const float* w2s = (const float*)d_in[3];
  const float* b2s = (const float*)d_in[4];
  const float* w1c = (const float*)d_in[5];
  const float* b1c = (const float*)d_in[6];
  const float* w2c = (const float*)d_in[7];
  const float* b2c = (const float*)d_in[8];

  float* out = (float*)d_out;
  float* pos = out;                   // (4,2)
  float* sclo = out + 8;              // (4,)
  float* scores = out + 12;           // (4,1,64,64)
  float* scales = out + 12 + 16384;   // (4,1,64,64)
  float* offsets = out + 12 + 32768;  // (4,2,64,64)

  char* ws = (char*)d_ws;
  float* st_scl = (float*)(ws + 0);       // 36 KB
  float* st_shf = (float*)(ws + 36864);   // 36 KB
  int* topidx = (int*)(ws + 73728);       // 1 MB
  float* rs = (float*)(ws + 1122304);     // 8.39 MB (dead after k_topk)
  float* vbuf = rs;                       // 18.87 MB, overlaps rs (ok)
  float* wT = (float*)(ws + 19996672);    // 884 KB (big-conv transposed w)
  float* wmT = (float*)(ws + 20881408);   // 54 KB (MLP transposed w)
  float* xs = (float*)(ws + 20971520);    // 4.19 MB
  float* xc = (float*)(ws + 25165824);    // 4.19 MB  (total 29.4 MB)
  // t1/t2 reuse dead regions (stream-ordered):
  float* t1s = vbuf;                         // vbuf dead after MLPs
  float* t1o = (float*)((char*)vbuf + 4194304);
  float* t1c = (float*)((char*)vbuf + 8388608);
  float* t2c = (float*)((char*)vbuf + 12582912);
  float* t2s = xs;                           // xs dead after conv layer 1
  float* t2o = xc;                           // xc dead after conv layer 1

  k_wx<<<149, 256, 0, stream>>>((const float*)d_in[9], (const float*)d_in[11],
                                (const float*)d_in[15], (const float*)d_in[17],
                                (const float*)d_in[21], (const float*)d_in[23],
                                wT, w1s, w2s, w1c, w2c, wmT);
  k_stats<<<9216, 256, 0, stream>>>(corr, st_scl, st_shf);
  k_refscore<<<2048, 256, 0, stream>>>(corr, st_scl, st_shf, rs);
  k_topk<<<256, 256, 0, stream>>>(rs, topidx);
  k_gather<<<4608, 256, 0, stream>>>(corr, st_scl, st_shf, topidx, vbuf);
  k_mlps<<<256, 256, 0, stream>>>(vbuf, wmT, b1s, wmT + 4608, b2s, xs);
  k_mlpc<<<256, 256, 0, stream>>>(vbuf, wmT + 8704, b1c, wmT + 9472, b2c, xc);
  // conv layer 1 (all heads): xs->t1s, xc->t1o, xc->t1c
  k_conv3h<true><<<768, 256, 0, stream>>>(
      xs, xc, xc, wT, wT + 2 * 36864, wT + 4 * 36864,
      (const float*)d_in[10], (const float*)d_in[16], (const float*)d_in[22],
      t1s, t1o, t1c);
  // conv layer 2 (all heads): t1*->t2*
  k_conv3h<true><<<768, 256, 0, stream>>>(
      t1s, t1o, t1c, wT + 1 * 36864, wT + 3 * 36864, wT + 5 * 36864,
      (const float*)d_in[12], (const float*)d_in[18], (const float*)d_in[24],
      t2s, t2o, t2c);
  // conv layer 3 (all heads): t2* -> scales/offsets/scores
  k_convSh<<<768, 256, 0, stream>>>(
      t2s, t2o, t2c, (const float*)d_in[13], (const float*)d_in[19],
      (const float*)d_in[25], (const float*)d_in[14], (const float*)d_in[20],
      (const float*)d_in[26], scales, offsets, scores);

  k_final<<<4, 256, 0, stream>>>(scores, scales, offsets, pos, sclo);
}